// Round 13
// baseline (1563.448 us; speedup 1.0000x reference)
//
#include <hip/hip_runtime.h>

#define NN    4096
#define BIGF  1e8f
// Scaled domain: R' = R * K2, K2 = (1/GAMMA)*log2(e).
// softmin'(a,b,c) = m - log2(exp2(m-a)+exp2(m-b)+exp2(m-c)); loss = R'/K2.
#define SQK2f 12.0112245225638540f    // sqrt(K2)
#define BIGK  1.4426950408889634e10f  // 1e8 * K2
#define IK2f  0.00693147180559945309f // 1/K2 = GAMMA*ln2
#define NBLK  32       // stripes of 128 rows (64 lanes x R=2), skew 63 (r9 mapping)
#define NCI   130      // chunks of 32 steps: s = 0..4159
#define OUTS  4158     // lane63: j = 4095 at s = 4095 + 63
#define SENTU 0xFFFFFFFFu   // NaN sentinel: DP values are never NaN

// ---------------- fallback: single-block diagonal kernel (verified r1) ----------------
__global__ __launch_bounds__(1024) void dilate_sdtw(const float* __restrict__ pred,
                                                    const float* __restrict__ target,
                                                    float* __restrict__ out) {
    __shared__ float t_s[NN];
    __shared__ float p_s[NN];
    __shared__ float bufA[NN];
    __shared__ float bufB[NN];
    __shared__ float bufC[NN];
    const int tid = threadIdx.x;
    for (int i = tid; i < NN; i += 1024) {
        t_s[i] = target[i]; p_s[i] = pred[i];
        bufA[i] = BIGF; bufB[i] = BIGF; bufC[i] = BIGF;
    }
    __syncthreads();
    float* r2 = bufA; float* r1 = bufB; float* rn = bufC;
    for (int k = 0; k < 2 * NN - 1; ++k) {
        int ilo = k - (NN - 1); if (ilo < 0) ilo = 0;
        int ihi = (k < NN - 1) ? k : (NN - 1);
        for (int i = ilo + tid; i <= ihi; i += 1024) {
            const int j = k - i;
            float diff = t_s[i] - p_s[j];
            float d = diff * diff;
            float a = (i >= 1 && j >= 1) ? r2[i - 1] : ((k == 0) ? 0.0f : BIGF);
            float b = (i >= 1) ? r1[i - 1] : BIGF;
            float c = (j >= 1) ? r1[i] : BIGF;
            float m = fminf(a, fminf(b, c));
            float s = __expf((m - a) * 100.0f) + __expf((m - b) * 100.0f) + __expf((m - c) * 100.0f);
            rn[i] = d + m - 0.01f * __logf(s);
        }
        __syncthreads();
        float* tmp = r2; r2 = r1; r1 = rn; rn = tmp;
    }
    if (tid == 0) out[0] = r1[NN - 1];
}

// ---- r9 core (verified 858 us, absmax 0.0), repacked 8 waves/block for SIMD-sharing TLP ----

__device__ __forceinline__ float softmin3s(float a, float b, float c) {
    float m = fminf(a, fminf(b, c));
    float e = __builtin_amdgcn_exp2f(m - a)
            + __builtin_amdgcn_exp2f(m - b)
            + __builtin_amdgcn_exp2f(m - c);
    return m - __builtin_amdgcn_logf(e);   // logf builtin = log2
}

// lane l <- lane l-1, whole wave, pure VALU (verified r8/r9):
// row_shr:1 covers lanes 1-15 of each 16-row; row_bcast:15 covers lanes 16/32/48.
__device__ __forceinline__ float nbr1(float v, bool bsel) {
    int iv = __float_as_int(v);
    float a = __int_as_float(__builtin_amdgcn_update_dpp(iv, iv, 0x111, 0xF, 0xF, false)); // row_shr:1
    float b = __int_as_float(__builtin_amdgcn_update_dpp(iv, iv, 0x142, 0xF, 0xF, false)); // row_bcast:15
    return bsel ? b : a;
}

__device__ __forceinline__ void bput(float* p, float v) {
    __hip_atomic_store((unsigned int*)p, __float_as_uint(v),
                       __ATOMIC_RELAXED, __HIP_MEMORY_SCOPE_AGENT);
}
__device__ __forceinline__ unsigned int bgetu(const float* p) {
    return __hip_atomic_load((const unsigned int*)p,
                             __ATOMIC_RELAXED, __HIP_MEMORY_SCOPE_AGENT);
}

// issue 32 relaxed loads into regs; no use -> wait deferred to uvalid
__device__ __forceinline__ void uissue(const float* src, float* dst) {
#pragma unroll
    for (int q = 0; q < 32; ++q) dst[q] = __uint_as_float(bgetu(src + q));
}
__device__ __forceinline__ bool uvalid(const float* dst) {
    bool ok = true;
#pragma unroll
    for (int q = 0; q < 32; ++q) ok &= (__float_as_uint(dst[q]) != SENTU);
    return ok;
}
__device__ __forceinline__ void upoll(const float* src, float* dst) {
    for (;;) {
        uissue(src, dst);
        if (uvalid(dst)) return;
        __builtin_amdgcn_s_sleep(1);
    }
}

// p for one chunk: 32 columns from per-lane base (clamped), scalar LDS reads
__device__ __forceinline__ void pload(const float* p_s, int base, float* dst) {
#pragma unroll
    for (int q = 0; q < 32; ++q) {
        int idx = base + q;
        idx = idx < 0 ? 0 : (idx > NN - 1 ? NN - 1 : idx);
        dst[q] = p_s[idx];
    }
}

template<bool TOP, bool BOT, bool EDGE>
__device__ __forceinline__ void chunk32(
    int cs, int lane, bool l0, bool bsel, float t0, float t1,
    float& v0, float& v1, float& u1, float& u2, float upl,
    float4& acc, const float* upc, const float* pc,
    float* __restrict__ bnd_my, float* __restrict__ outp)
{
#pragma unroll
    for (int u = 0; u < 32; ++u) {
        const int s = cs + u;
        const int j = s - lane;          // off(l) = l, skew 63
        float a, b;
        if (TOP) {
            a = l0 ? ((s == 0) ? 0.0f : BIGK) : u2;
            b = l0 ? BIGK : u1;
        } else {
            float upj  = upc[u];
            float upjm = (u == 0) ? upl : upc[u - 1];
            a = l0 ? upjm : u2;
            b = l0 ? upj  : u1;
        }
        float pj = pc[u];
        float d0 = t0 - pj;
        float val0 = fmaf(d0, d0, softmin3s(a, b, v0));      // row 2l, col j
        float d1 = t1 - pj;
        float val1 = fmaf(d1, d1, softmin3s(v0, val0, v1));  // row 2l+1, col j
        if (EDGE) {
            bool vj = (unsigned)j < (unsigned)NN;
            val0 = vj ? val0 : BIGK;
            val1 = vj ? val1 : BIGK;
        }
        if (!BOT) {
            // lane63: j = s-63, j%4 == (u+1)%4. collect 4 cols, publish when j%4==3 (u%4==2)
            switch ((u + 1) & 3) {
                case 0: acc.x = val1; break;
                case 1: acc.y = val1; break;
                case 2: acc.z = val1; break;
                case 3: acc.w = val1; break;
            }
            if ((u & 3) == 2) {
                int base = j - 3;
                if (lane == 63 && (!EDGE || (unsigned)base <= (unsigned)(NN - 4))) {
                    bput(bnd_my + base + 0, acc.x);
                    bput(bnd_my + base + 1, acc.y);
                    bput(bnd_my + base + 2, acc.z);
                    bput(bnd_my + base + 3, acc.w);
                }
            }
        } else if (EDGE) {
            if (lane == 63 && s == OUTS) outp[0] = val1 * IK2f;
        }
        v0 = val0; v1 = val1;
        u2 = u1;
        u1 = nbr1(val1, bsel);   // neighbor's v1 @ s, consumed at s+1 (pure VALU)
    }
}

template<bool TOP, bool BOT>
__device__ __forceinline__ void chunk_iter(
    int ci, int lane, bool l0, bool bsel, float t0, float t1,
    float& v0, float& v1, float& u1, float& u2, float& upl,
    float4& acc,
    float* upC, float* upN, float* pcC, float* pcN,
    const float* p_s, const float* __restrict__ bnd_up, float* __restrict__ bnd_my,
    float* __restrict__ outp)
{
    const int cs = 32 * ci;
    if (!TOP && cs < NN) {
        if (!uvalid(upC)) upoll(bnd_up + cs, upC);       // fast path: issued last chunk
        if (cs + 32 < NN) uissue(bnd_up + cs + 32, upN); // issue for next chunk, no wait
    }
    if (ci + 1 < NCI) pload(p_s, cs + 32 - lane, pcN);

    const bool edge = (ci < 2) || (ci >= 128);
    if (edge) chunk32<TOP, BOT, true >(cs, lane, l0, bsel, t0, t1, v0, v1, u1, u2,
                                       upl, acc, upC, pcC, bnd_my, outp);
    else      chunk32<TOP, BOT, false>(cs, lane, l0, bsel, t0, t1, v0, v1, u1, u2,
                                       upl, acc, upC, pcC, bnd_my, outp);
    if (!TOP) upl = upC[31];
}

template<bool TOP, bool BOT>
__device__ void stripe(int b, int lane, const float* __restrict__ target,
                       const float* p_s, float* bnd, float* outp)
{
    const float t0 = target[128 * b + 2 * lane]     * SQK2f;
    const float t1 = target[128 * b + 2 * lane + 1] * SQK2f;
    float* bnd_my = bnd + (size_t)b * NN;
    const float* bnd_up = bnd + (size_t)(b - 1) * NN;
    const bool l0 = (lane == 0);
    const bool bsel = (lane != 0) && ((lane & 15) == 0);   // lanes 16/32/48: row-crossing

    float v0 = BIGK, v1 = BIGK, u1 = BIGK, u2 = BIGK, upl = BIGK;
    float4 acc = {BIGK, BIGK, BIGK, BIGK};
    float upA[32], upB[32];
    float pcA[32], pcB[32];

    pload(p_s, -lane, pcA);
    if (!TOP) uissue(bnd_up, upA);   // prologue issue for chunk 0

    for (int cp = 0; cp < NCI / 2; ++cp) {
        chunk_iter<TOP, BOT>(2 * cp,     lane, l0, bsel, t0, t1, v0, v1, u1, u2, upl, acc,
                             upA, upB, pcA, pcB, p_s, bnd_up, bnd_my, outp);
        chunk_iter<TOP, BOT>(2 * cp + 1, lane, l0, bsel, t0, t1, v0, v1, u1, u2, upl, acc,
                             upB, upA, pcB, pcA, p_s, bnd_up, bnd_my, outp);
    }
}

// 8 waves per block = 8 adjacent stripes; 4 blocks cover 32 stripes.
// Two waves land on each SIMD (round-robin) and hide each other's dependency latency.
__global__ __launch_bounds__(512, 1) void sdtw_pipe13(const float* __restrict__ pred,
                                                      const float* __restrict__ target,
                                                      float* __restrict__ out,
                                                      float* __restrict__ bnd)
{
    __shared__ float p_s[NN];
    const int tid  = threadIdx.x;
    const int lane = tid & 63;
    const int wave = tid >> 6;
    for (int i = tid; i < NN; i += 512) p_s[i] = pred[i] * SQK2f;
    __syncthreads();

    const int b = blockIdx.x * 8 + wave;   // adjacent stripes share the CU/L2
    if (b == 0)                stripe<true , false>(b, lane, target, p_s, bnd, out);
    else if (b == NBLK - 1)    stripe<false, true >(b, lane, target, p_s, bnd, out);
    else                       stripe<false, false>(b, lane, target, p_s, bnd, out);
}

extern "C" void kernel_launch(void* const* d_in, const int* in_sizes, int n_in,
                              void* d_out, int out_size, void* d_ws, size_t ws_size,
                              hipStream_t stream) {
    const float* pred   = (const float*)d_in[0];
    const float* target = (const float*)d_in[1];
    float* out = (float*)d_out;

    const size_t need = (size_t)NBLK * NN * sizeof(float);
    if (ws_size >= need) {
        float* bnd = (float*)d_ws;
        hipMemsetAsync(d_ws, 0xFF, need, stream);   // NaN-sentinel fill (value-carried readiness)
        sdtw_pipe13<<<dim3(4), dim3(512), 0, stream>>>(pred, target, out, bnd);
    } else {
        dilate_sdtw<<<dim3(1), dim3(1024), 0, stream>>>(pred, target, out);
    }
}

// Round 14
// 945.323 us; speedup vs baseline: 1.6539x; 1.6539x over previous
//
#include <hip/hip_runtime.h>

#define NN    4096
#define BIGF  1e8f
// Scaled domain: R' = R * K2, K2 = (1/GAMMA)*log2(e).
// softmin'(a,b,c) = m - log2(1 + exp2(m-med) + exp2(m-max)); loss = R'/K2.
#define SQK2f 12.0112245225638540f    // sqrt(K2)
#define BIGK  1.4426950408889634e10f  // 1e8 * K2
#define IK2f  0.00693147180559945309f // 1/K2 = GAMMA*ln2
#define NBLK  32       // stripes of 128 rows (64 lanes x R=2), skew 63 (r9 mapping)
#define NCI   130      // chunks of 32 steps: s = 0..4159
#define OUTS  4158     // lane63: j = 4095 at s = 4095 + 63
#define SENTU 0xFFFFFFFFu   // NaN sentinel: DP values are never NaN

// ---------------- fallback: single-block diagonal kernel (verified r1) ----------------
__global__ __launch_bounds__(1024) void dilate_sdtw(const float* __restrict__ pred,
                                                    const float* __restrict__ target,
                                                    float* __restrict__ out) {
    __shared__ float t_s[NN];
    __shared__ float p_s[NN];
    __shared__ float bufA[NN];
    __shared__ float bufB[NN];
    __shared__ float bufC[NN];
    const int tid = threadIdx.x;
    for (int i = tid; i < NN; i += 1024) {
        t_s[i] = target[i]; p_s[i] = pred[i];
        bufA[i] = BIGF; bufB[i] = BIGF; bufC[i] = BIGF;
    }
    __syncthreads();
    float* r2 = bufA; float* r1 = bufB; float* rn = bufC;
    for (int k = 0; k < 2 * NN - 1; ++k) {
        int ilo = k - (NN - 1); if (ilo < 0) ilo = 0;
        int ihi = (k < NN - 1) ? k : (NN - 1);
        for (int i = ilo + tid; i <= ihi; i += 1024) {
            const int j = k - i;
            float diff = t_s[i] - p_s[j];
            float d = diff * diff;
            float a = (i >= 1 && j >= 1) ? r2[i - 1] : ((k == 0) ? 0.0f : BIGF);
            float b = (i >= 1) ? r1[i - 1] : BIGF;
            float c = (j >= 1) ? r1[i] : BIGF;
            float m = fminf(a, fminf(b, c));
            float s = __expf((m - a) * 100.0f) + __expf((m - b) * 100.0f) + __expf((m - c) * 100.0f);
            rn[i] = d + m - 0.01f * __logf(s);
        }
        __syncthreads();
        float* tmp = r2; r2 = r1; r1 = rn; rn = tmp;
    }
    if (tid == 0) out[0] = r1[NN - 1];
}

// ---- r9 core, instruction-trimmed: DPP old-operand boundary injection + 3-trans softmin ----

__device__ __forceinline__ float softmin3s(float a, float b, float c) {
    float m  = fminf(a, fminf(b, c));                 // -> v_min3_f32
    float md = __builtin_amdgcn_fmed3f(a, b, c);      // v_med3_f32
    float mx = fmaxf(a, fmaxf(b, c));                 // -> v_max3_f32
    float e  = 1.0f + (__builtin_amdgcn_exp2f(m - md) + __builtin_amdgcn_exp2f(m - mx));
    return m - __builtin_amdgcn_logf(e);              // logf builtin = log2
}

__device__ __forceinline__ void bput(float* p, float v) {
    __hip_atomic_store((unsigned int*)p, __float_as_uint(v),
                       __ATOMIC_RELAXED, __HIP_MEMORY_SCOPE_AGENT);
}
__device__ __forceinline__ unsigned int bgetu(const float* p) {
    return __hip_atomic_load((const unsigned int*)p,
                             __ATOMIC_RELAXED, __HIP_MEMORY_SCOPE_AGENT);
}

// issue 32 relaxed loads into regs; no use -> wait deferred to uvalid
__device__ __forceinline__ void uissue(const float* src, float* dst) {
#pragma unroll
    for (int q = 0; q < 32; ++q) dst[q] = __uint_as_float(bgetu(src + q));
}
__device__ __forceinline__ bool uvalid(const float* dst) {
    bool ok = true;
#pragma unroll
    for (int q = 0; q < 32; ++q) ok &= (__float_as_uint(dst[q]) != SENTU);
    return ok;
}
__device__ __forceinline__ void upoll(const float* src, float* dst) {
    for (;;) {
        uissue(src, dst);
        if (uvalid(dst)) return;
        __builtin_amdgcn_s_sleep(1);
    }
}

// p for one chunk: 32 columns from per-lane base (clamped), scalar LDS reads
__device__ __forceinline__ void pload(const float* p_s, int base, float* dst) {
#pragma unroll
    for (int q = 0; q < 32; ++q) {
        int idx = base + q;
        idx = idx < 0 ? 0 : (idx > NN - 1 ? NN - 1 : idx);
        dst[q] = p_s[idx];
    }
}

template<bool TOP, bool BOT, bool EDGE>
__device__ __forceinline__ void chunk32(
    int cs, int lane, bool bsel, float t0, float t1,
    float& v0, float& v1, float& u1, float& u2,
    float4& acc, const float* upc, const float* pc,
    float* __restrict__ bnd_my, float* __restrict__ outp)
{
#pragma unroll
    for (int u = 0; u < 32; ++u) {
        const int s = cs + u;
        const int j = s - lane;          // off(l) = l, skew 63
        // a,b come straight from the register chain; lane-0 boundary values were
        // injected into u1 via the DPP old-operand (below) / per-chunk fixup.
        float pj = pc[u];
        float d0 = t0 - pj;
        float val0 = fmaf(d0, d0, softmin3s(u2, u1, v0));    // row 2l, col j
        float d1 = t1 - pj;
        float val1 = fmaf(d1, d1, softmin3s(v0, val0, v1));  // row 2l+1, col j
        if (EDGE) {
            bool vj = (unsigned)j < (unsigned)NN;
            val0 = vj ? val0 : BIGK;
            val1 = vj ? val1 : BIGK;
        }
        if (!BOT) {
            // lane63: j = s-63, j%4 == (u+1)%4. collect 4 cols, publish when j%4==3 (u%4==2)
            switch ((u + 1) & 3) {
                case 0: acc.x = val1; break;
                case 1: acc.y = val1; break;
                case 2: acc.z = val1; break;
                case 3: acc.w = val1; break;
            }
            if ((u & 3) == 2) {
                int base = j - 3;
                if (lane == 63 && (!EDGE || (unsigned)base <= (unsigned)(NN - 4))) {
                    bput(bnd_my + base + 0, acc.x);
                    bput(bnd_my + base + 1, acc.y);
                    bput(bnd_my + base + 2, acc.z);
                    bput(bnd_my + base + 3, acc.w);
                }
            }
        } else if (EDGE) {
            if (lane == 63 && s == OUTS) outp[0] = val1 * IK2f;
        }
        v0 = val0; v1 = val1;
        u2 = u1;
        // u1 for step s+1: neighbor val1 via row_shr:1; lane 0 receives up[s+1]
        // through the DPP old operand (TOP: BIGK). Lanes 16/32/48 fixed by bcast15.
        {
            float oldv = TOP ? BIGK : upc[(u + 1) & 31];   // u=31 placeholder, fixed at next chunk start
            int iv = __float_as_int(val1);
            float sh = __int_as_float(__builtin_amdgcn_update_dpp(
                __float_as_int(oldv), iv, 0x111, 0xF, 0xF, false));  // row_shr:1, old kept at row heads
            float bc = __int_as_float(__builtin_amdgcn_update_dpp(
                iv, iv, 0x142, 0xF, 0xF, false));                    // row_bcast:15
            u1 = bsel ? bc : sh;
        }
    }
}

template<bool TOP, bool BOT>
__device__ __forceinline__ void chunk_iter(
    int ci, int lane, bool l0, bool bsel, float t0, float t1,
    float& v0, float& v1, float& u1, float& u2,
    float4& acc,
    float* upC, float* upN, float* pcC, float* pcN,
    const float* p_s, const float* __restrict__ bnd_up, float* __restrict__ bnd_my,
    float* __restrict__ outp)
{
    const int cs = 32 * ci;
    if (!TOP && cs < NN) {
        if (!uvalid(upC)) upoll(bnd_up + cs, upC);       // fast path: issued last chunk
        if (cs + 32 < NN) uissue(bnd_up + cs + 32, upN); // issue for next chunk, no wait
        u1 = l0 ? upC[0] : u1;   // lane-0 b for this chunk's step 0 (wrap fixup)
    }
    if (ci + 1 < NCI) pload(p_s, cs + 32 - lane, pcN);

    const bool edge = (ci < 2) || (ci >= 128);
    if (edge) chunk32<TOP, BOT, true >(cs, lane, bsel, t0, t1, v0, v1, u1, u2,
                                       acc, upC, pcC, bnd_my, outp);
    else      chunk32<TOP, BOT, false>(cs, lane, bsel, t0, t1, v0, v1, u1, u2,
                                       acc, upC, pcC, bnd_my, outp);
}

template<bool TOP, bool BOT>
__device__ void stripe(int b, int lane, const float* __restrict__ target,
                       const float* p_s, float* bnd, float* outp)
{
    const float t0 = target[128 * b + 2 * lane]     * SQK2f;
    const float t1 = target[128 * b + 2 * lane + 1] * SQK2f;
    float* bnd_my = bnd + (size_t)b * NN;
    const float* bnd_up = bnd + (size_t)(b - 1) * NN;
    const bool l0 = (lane == 0);
    const bool bsel = (lane != 0) && ((lane & 15) == 0);   // lanes 16/32/48: row-crossing

    // virtual origin R[-1][-1]=0 lives in u2's init for (0,0); all else starts at +inf
    float v0 = BIGK, v1 = BIGK, u1 = BIGK;
    float u2 = (TOP && l0) ? 0.0f : BIGK;
    float4 acc = {BIGK, BIGK, BIGK, BIGK};
    float upA[32], upB[32];
    float pcA[32], pcB[32];

    pload(p_s, -lane, pcA);
    if (!TOP) uissue(bnd_up, upA);   // prologue issue for chunk 0

    for (int cp = 0; cp < NCI / 2; ++cp) {
        chunk_iter<TOP, BOT>(2 * cp,     lane, l0, bsel, t0, t1, v0, v1, u1, u2, acc,
                             upA, upB, pcA, pcB, p_s, bnd_up, bnd_my, outp);
        chunk_iter<TOP, BOT>(2 * cp + 1, lane, l0, bsel, t0, t1, v0, v1, u1, u2, acc,
                             upB, upA, pcB, pcA, p_s, bnd_up, bnd_my, outp);
    }
}

__global__ __launch_bounds__(64, 1) void sdtw_pipe14(const float* __restrict__ pred,
                                                     const float* __restrict__ target,
                                                     float* __restrict__ out,
                                                     float* __restrict__ bnd)
{
    __shared__ float p_s[NN];
    const int lane = threadIdx.x;
    const int bid = blockIdx.x;
    const int b = (bid & 7) * 4 + (bid >> 3);   // group stripe-neighbors per XCD
    for (int i = lane; i < NN; i += 64) p_s[i] = pred[i] * SQK2f;
    __syncthreads();
    if (b == 0)                stripe<true , false>(b, lane, target, p_s, bnd, out);
    else if (b == NBLK - 1)    stripe<false, true >(b, lane, target, p_s, bnd, out);
    else                       stripe<false, false>(b, lane, target, p_s, bnd, out);
}

extern "C" void kernel_launch(void* const* d_in, const int* in_sizes, int n_in,
                              void* d_out, int out_size, void* d_ws, size_t ws_size,
                              hipStream_t stream) {
    const float* pred   = (const float*)d_in[0];
    const float* target = (const float*)d_in[1];
    float* out = (float*)d_out;

    const size_t need = (size_t)NBLK * NN * sizeof(float);
    if (ws_size >= need) {
        float* bnd = (float*)d_ws;
        hipMemsetAsync(d_ws, 0xFF, need, stream);   // NaN-sentinel fill (value-carried readiness)
        sdtw_pipe14<<<dim3(NBLK), dim3(64), 0, stream>>>(pred, target, out, bnd);
    } else {
        dilate_sdtw<<<dim3(1), dim3(1024), 0, stream>>>(pred, target, out);
    }
}

// Round 15
// 882.949 us; speedup vs baseline: 1.7707x; 1.0706x over previous
//
#include <hip/hip_runtime.h>

#define NN    4096
#define BIGF  1e8f
// Scaled domain: R' = R * K2, K2 = (1/GAMMA)*log2(e).
// softmin'(a,b,c) = m - log2(exp2(m-a)+exp2(m-b)+exp2(m-c)); loss = R'/K2.
#define SQK2f 12.0112245225638540f    // sqrt(K2)
#define BIGK  1.4426950408889634e10f  // 1e8 * K2
#define IK2f  0.00693147180559945309f // 1/K2 = GAMMA*ln2
#define NBLK  32       // blocks; 2 waves each = 64 stripes of 64 rows (R=1)
#define NCI   130      // chunks of 32 steps: s = 0..4159
#define OUTS  4158     // lane63 (row 4095): j = 4095 at s = 4095 + 63
#define SENTU 0xFFFFFFFFu   // NaN sentinel: DP values are never NaN

#define CONS_NONE 0
#define CONS_GLB  1
#define CONS_LDS  2
#define PUB_LDS   0
#define PUB_GLB   1

// ---------------- fallback: single-block diagonal kernel (verified r1) ----------------
__global__ __launch_bounds__(1024) void dilate_sdtw(const float* __restrict__ pred,
                                                    const float* __restrict__ target,
                                                    float* __restrict__ out) {
    __shared__ float t_s[NN];
    __shared__ float p_s[NN];
    __shared__ float bufA[NN];
    __shared__ float bufB[NN];
    __shared__ float bufC[NN];
    const int tid = threadIdx.x;
    for (int i = tid; i < NN; i += 1024) {
        t_s[i] = target[i]; p_s[i] = pred[i];
        bufA[i] = BIGF; bufB[i] = BIGF; bufC[i] = BIGF;
    }
    __syncthreads();
    float* r2 = bufA; float* r1 = bufB; float* rn = bufC;
    for (int k = 0; k < 2 * NN - 1; ++k) {
        int ilo = k - (NN - 1); if (ilo < 0) ilo = 0;
        int ihi = (k < NN - 1) ? k : (NN - 1);
        for (int i = ilo + tid; i <= ihi; i += 1024) {
            const int j = k - i;
            float diff = t_s[i] - p_s[j];
            float d = diff * diff;
            float a = (i >= 1 && j >= 1) ? r2[i - 1] : ((k == 0) ? 0.0f : BIGF);
            float b = (i >= 1) ? r1[i - 1] : BIGF;
            float c = (j >= 1) ? r1[i] : BIGF;
            float m = fminf(a, fminf(b, c));
            float s = __expf((m - a) * 100.0f) + __expf((m - b) * 100.0f) + __expf((m - c) * 100.0f);
            rn[i] = d + m - 0.01f * __logf(s);
        }
        __syncthreads();
        float* tmp = r2; r2 = r1; r1 = rn; rn = tmp;
    }
    if (tid == 0) out[0] = r1[NN - 1];
}

// ---- R=1 lane-systolic, 2 waves/block, LDS (intra-block) + global (inter-block) sync ----

__device__ __forceinline__ float softmin3s(float a, float b, float c) {
    float m = fminf(a, fminf(b, c));
    float e = __builtin_amdgcn_exp2f(m - a)
            + __builtin_amdgcn_exp2f(m - b)
            + __builtin_amdgcn_exp2f(m - c);
    return m - __builtin_amdgcn_logf(e);   // logf builtin = log2
}

// lane l <- lane l-1, whole wave, pure VALU (verified r8/r9):
// row_shr:1 covers lanes 1-15 of each 16-row; row_bcast:15 covers lanes 16/32/48.
__device__ __forceinline__ float nbr1(float v, bool bsel) {
    int iv = __float_as_int(v);
    float a = __int_as_float(__builtin_amdgcn_update_dpp(iv, iv, 0x111, 0xF, 0xF, false)); // row_shr:1
    float b = __int_as_float(__builtin_amdgcn_update_dpp(iv, iv, 0x142, 0xF, 0xF, false)); // row_bcast:15
    return bsel ? b : a;
}

__device__ __forceinline__ void bput(float* p, float v) {
    __hip_atomic_store((unsigned int*)p, __float_as_uint(v),
                       __ATOMIC_RELAXED, __HIP_MEMORY_SCOPE_AGENT);
}
__device__ __forceinline__ unsigned int bgetu(const float* p) {
    return __hip_atomic_load((const unsigned int*)p,
                             __ATOMIC_RELAXED, __HIP_MEMORY_SCOPE_AGENT);
}
// LDS value-carried sync (tear-proof: any partial read still contains sentinels)
__device__ __forceinline__ void lput(float* p, float v) {
    __hip_atomic_store((unsigned int*)p, __float_as_uint(v),
                       __ATOMIC_RELAXED, __HIP_MEMORY_SCOPE_WORKGROUP);
}
__device__ __forceinline__ unsigned int lgetu(const float* p) {
    return __hip_atomic_load((const unsigned int*)p,
                             __ATOMIC_RELAXED, __HIP_MEMORY_SCOPE_WORKGROUP);
}
__device__ __forceinline__ void lpoll8(const float* lb, float* dst) {
    for (;;) {
        bool ok = true;
#pragma unroll
        for (int q = 0; q < 8; ++q) {
            unsigned int x = lgetu(lb + q);
            dst[q] = __uint_as_float(x);
            ok &= (x != SENTU);
        }
        if (ok) return;
        __builtin_amdgcn_s_sleep(1);
    }
}

// global: issue 32 relaxed loads; wait deferred to uvalid (r9 verbatim)
__device__ __forceinline__ void uissue(const float* src, float* dst) {
#pragma unroll
    for (int q = 0; q < 32; ++q) dst[q] = __uint_as_float(bgetu(src + q));
}
__device__ __forceinline__ bool uvalid(const float* dst) {
    bool ok = true;
#pragma unroll
    for (int q = 0; q < 32; ++q) ok &= (__float_as_uint(dst[q]) != SENTU);
    return ok;
}
__device__ __forceinline__ void upoll(const float* src, float* dst) {
    for (;;) {
        uissue(src, dst);
        if (uvalid(dst)) return;
        __builtin_amdgcn_s_sleep(1);
    }
}

// p for one chunk: 32 columns from per-lane base (clamped), scalar LDS reads
__device__ __forceinline__ void pload(const float* p_s, int base, float* dst) {
#pragma unroll
    for (int q = 0; q < 32; ++q) {
        int idx = base + q;
        idx = idx < 0 ? 0 : (idx > NN - 1 ? NN - 1 : idx);
        dst[q] = p_s[idx];
    }
}

template<int CONS, int PUB, bool BOT, bool EDGE, int UO>
__device__ __forceinline__ void chunk8(
    int cs, int lane, bool l0, bool bsel, float t,
    float& v, float& u1, float& u2, float upl,
    float4& acc, const float* upc, const float* pc,
    float* __restrict__ bnd_my, float* lds_out, float* __restrict__ outp)
{
#pragma unroll
    for (int uu = 0; uu < 8; ++uu) {
        const int u = UO + uu;
        const int s = cs + u;
        const int j = s - lane;          // off(l) = l, skew 63
        float a, b;
        if (CONS == CONS_NONE) {
            a = l0 ? ((s == 0) ? 0.0f : BIGK) : u2;   // virtual origin at (0,0)
            b = l0 ? BIGK : u1;
        } else {
            float upj  = upc[u];
            float upjm = (u == 0) ? upl : upc[u - 1];
            a = l0 ? upjm : u2;
            b = l0 ? upj  : u1;
        }
        float d = t - pc[u];
        float val = fmaf(d, d, softmin3s(a, b, v));   // row (lane), col j
        if (EDGE) val = ((unsigned)j < (unsigned)NN) ? val : BIGK;
        if (!BOT) {
            // lane63: j = s-63, j%4 == (u+1)%4. collect 4 cols, publish when j%4==3 (u%4==2)
            switch ((u + 1) & 3) {
                case 0: acc.x = val; break;
                case 1: acc.y = val; break;
                case 2: acc.z = val; break;
                case 3: acc.w = val; break;
            }
            if ((u & 3) == 2) {
                const int base = j - 3;
                if (lane == 63 && (!EDGE || (unsigned)base <= (unsigned)(NN - 4))) {
                    if (PUB == PUB_GLB) {
                        bput(bnd_my + base + 0, acc.x);
                        bput(bnd_my + base + 1, acc.y);
                        bput(bnd_my + base + 2, acc.z);
                        bput(bnd_my + base + 3, acc.w);
                    } else {
                        lput(lds_out + base + 0, acc.x);
                        lput(lds_out + base + 1, acc.y);
                        lput(lds_out + base + 2, acc.z);
                        lput(lds_out + base + 3, acc.w);
                    }
                }
            }
        } else if (EDGE) {
            if (lane == 63 && s == OUTS) outp[0] = val * IK2f;
        }
        v = val;
        u2 = u1;
        u1 = nbr1(val, bsel);            // lane l-1's val @ s, consumed at s+1
    }
}

template<int CONS, int PUB, bool BOT>
__device__ __forceinline__ void chunk_iter(
    int ci, int lane, bool l0, bool bsel, float t,
    float& v, float& u1, float& u2, float& upl,
    float4& acc,
    float* upC, float* upN, float* pcC, float* pcN,
    const float* p_s, const float* __restrict__ bnd_up, const float* lds_in,
    float* __restrict__ bnd_my, float* lds_out, float* __restrict__ outp)
{
    const int cs = 32 * ci;
    const bool haveUp = (cs < NN);
    if (CONS == CONS_GLB && haveUp) {
        if (!uvalid(upC)) upoll(bnd_up + cs, upC);       // fast path: issued last chunk
        if (cs + 32 < NN) uissue(bnd_up + cs + 32, upN); // issue next chunk, no wait
    }
    if (ci + 1 < NCI) pload(p_s, cs + 32 - lane, pcN);

    const bool edge = (ci < 2) || (ci >= 128);
#define SUBC(UO_) \
    do { \
        if (CONS == CONS_LDS && haveUp) lpoll8(lds_in + cs + UO_, upC + UO_); \
        if (edge) chunk8<CONS, PUB, BOT, true , UO_>(cs, lane, l0, bsel, t, v, u1, u2, upl, \
                                                     acc, upC, pcC, bnd_my, lds_out, outp); \
        else      chunk8<CONS, PUB, BOT, false, UO_>(cs, lane, l0, bsel, t, v, u1, u2, upl, \
                                                     acc, upC, pcC, bnd_my, lds_out, outp); \
    } while (0)
    SUBC(0); SUBC(8); SUBC(16); SUBC(24);
#undef SUBC
    if (CONS != CONS_NONE && haveUp) upl = upC[31];
}

template<int CONS, int PUB, bool BOT>
__device__ void stripe(int rowbase, int lane, const float* __restrict__ target,
                       const float* p_s, const float* __restrict__ bnd_up,
                       float* __restrict__ bnd_my, const float* lds_in, float* lds_out,
                       float* __restrict__ outp)
{
    const float t = target[rowbase + lane] * SQK2f;
    const bool l0 = (lane == 0);
    const bool bsel = (lane != 0) && ((lane & 15) == 0);   // lanes 16/32/48: row-crossing

    float v = BIGK, u1 = BIGK, u2 = BIGK, upl = BIGK;
    float4 acc = {BIGK, BIGK, BIGK, BIGK};
    float upA[32], upB[32];
    float pcA[32], pcB[32];

    pload(p_s, -lane, pcA);
    if (CONS == CONS_GLB) uissue(bnd_up, upA);   // prologue issue for chunk 0

    for (int cp = 0; cp < NCI / 2; ++cp) {
        chunk_iter<CONS, PUB, BOT>(2 * cp,     lane, l0, bsel, t, v, u1, u2, upl, acc,
                                   upA, upB, pcA, pcB, p_s, bnd_up, lds_in, bnd_my, lds_out, outp);
        chunk_iter<CONS, PUB, BOT>(2 * cp + 1, lane, l0, bsel, t, v, u1, u2, upl, acc,
                                   upB, upA, pcB, pcA, p_s, bnd_up, lds_in, bnd_my, lds_out, outp);
    }
}

__global__ __launch_bounds__(128, 1) void sdtw_pipe15(const float* __restrict__ pred,
                                                      const float* __restrict__ target,
                                                      float* __restrict__ out,
                                                      float* __restrict__ bnd)
{
    __shared__ float p_s[NN];
    __shared__ float lb[NN];     // intra-block boundary (wave0 bottom row -> wave1)
    const int tid = threadIdx.x;
    const int bid = blockIdx.x;
    const int B = (bid & 7) * 4 + (bid >> 3);   // group block-neighbors per XCD
    for (int i = tid; i < NN; i += 128) {
        p_s[i] = pred[i] * SQK2f;
        lb[i]  = __uint_as_float(SENTU);        // NaN-sentinel init
    }
    __syncthreads();

    const int wave = tid >> 6;
    const int lane = tid & 63;
    float* bnd_my = bnd + (size_t)B * NN;
    const float* bnd_up = bnd + (size_t)(B - 1) * NN;   // unused for B==0

    if (wave == 0) {
        // rows [128B, 128B+63]; consume prev block's global row, publish row 128B+63 to LDS
        if (B == 0) stripe<CONS_NONE, PUB_LDS, false>(0,       lane, target, p_s, nullptr, nullptr, nullptr, lb, out);
        else        stripe<CONS_GLB , PUB_LDS, false>(128 * B, lane, target, p_s, bnd_up,  nullptr, nullptr, lb, out);
    } else {
        // rows [128B+64, 128B+127]; consume LDS, publish row 128B+127 to global
        if (B == NBLK - 1) stripe<CONS_LDS, PUB_GLB, true >(128 * B + 64, lane, target, p_s, nullptr, bnd_my, lb, nullptr, out);
        else               stripe<CONS_LDS, PUB_GLB, false>(128 * B + 64, lane, target, p_s, nullptr, bnd_my, lb, nullptr, out);
    }
}

extern "C" void kernel_launch(void* const* d_in, const int* in_sizes, int n_in,
                              void* d_out, int out_size, void* d_ws, size_t ws_size,
                              hipStream_t stream) {
    const float* pred   = (const float*)d_in[0];
    const float* target = (const float*)d_in[1];
    float* out = (float*)d_out;

    const size_t need = (size_t)NBLK * NN * sizeof(float);
    if (ws_size >= need) {
        float* bnd = (float*)d_ws;
        hipMemsetAsync(d_ws, 0xFF, need, stream);   // NaN-sentinel fill (value-carried readiness)
        sdtw_pipe15<<<dim3(NBLK), dim3(128), 0, stream>>>(pred, target, out, bnd);
    } else {
        dilate_sdtw<<<dim3(1), dim3(1024), 0, stream>>>(pred, target, out);
    }
}

// Round 16
// 857.558 us; speedup vs baseline: 1.8231x; 1.0296x over previous
//
#include <hip/hip_runtime.h>

#define NN    4096
#define BIGF  1e8f
// Scaled domain: R' = R * K2, K2 = (1/GAMMA)*log2(e).
// softmin'(a,b,c) = m - log2(exp2(m-a)+exp2(m-b)+exp2(m-c)); loss = R'/K2.
#define SQK2f 12.0112245225638540f    // sqrt(K2)
#define BIGK  1.4426950408889634e10f  // 1e8 * K2
#define IK2f  0.00693147180559945309f // 1/K2 = GAMMA*ln2
#define NBLK  32       // stripes of 128 rows (64 lanes x R=2), skew 63 (r9 mapping)
#define SCH   16       // steps per chunk (halved vs r9: I-cache + fill-lag probe)
#define NCI   260      // chunks of 16 steps: s = 0..4159
#define OUTS  4158     // lane63: j = 4095 at s = 4095 + 63
#define SENTU 0xFFFFFFFFu   // NaN sentinel: DP values are never NaN

// ---------------- fallback: single-block diagonal kernel (verified r1) ----------------
__global__ __launch_bounds__(1024) void dilate_sdtw(const float* __restrict__ pred,
                                                    const float* __restrict__ target,
                                                    float* __restrict__ out) {
    __shared__ float t_s[NN];
    __shared__ float p_s[NN];
    __shared__ float bufA[NN];
    __shared__ float bufB[NN];
    __shared__ float bufC[NN];
    const int tid = threadIdx.x;
    for (int i = tid; i < NN; i += 1024) {
        t_s[i] = target[i]; p_s[i] = pred[i];
        bufA[i] = BIGF; bufB[i] = BIGF; bufC[i] = BIGF;
    }
    __syncthreads();
    float* r2 = bufA; float* r1 = bufB; float* rn = bufC;
    for (int k = 0; k < 2 * NN - 1; ++k) {
        int ilo = k - (NN - 1); if (ilo < 0) ilo = 0;
        int ihi = (k < NN - 1) ? k : (NN - 1);
        for (int i = ilo + tid; i <= ihi; i += 1024) {
            const int j = k - i;
            float diff = t_s[i] - p_s[j];
            float d = diff * diff;
            float a = (i >= 1 && j >= 1) ? r2[i - 1] : ((k == 0) ? 0.0f : BIGF);
            float b = (i >= 1) ? r1[i - 1] : BIGF;
            float c = (j >= 1) ? r1[i] : BIGF;
            float m = fminf(a, fminf(b, c));
            float s = __expf((m - a) * 100.0f) + __expf((m - b) * 100.0f) + __expf((m - c) * 100.0f);
            rn[i] = d + m - 0.01f * __logf(s);
        }
        __syncthreads();
        float* tmp = r2; r2 = r1; r1 = rn; rn = tmp;
    }
    if (tid == 0) out[0] = r1[NN - 1];
}

// ---- r9 core verbatim, chunk size 32 -> 16 (code-footprint + fill-lag probe) ----

__device__ __forceinline__ float softmin3s(float a, float b, float c) {
    float m = fminf(a, fminf(b, c));
    float e = __builtin_amdgcn_exp2f(m - a)
            + __builtin_amdgcn_exp2f(m - b)
            + __builtin_amdgcn_exp2f(m - c);
    return m - __builtin_amdgcn_logf(e);   // logf builtin = log2
}

// lane l <- lane l-1, whole wave, pure VALU (verified r8/r9):
// row_shr:1 covers lanes 1-15 of each 16-row; row_bcast:15 covers lanes 16/32/48.
__device__ __forceinline__ float nbr1(float v, bool bsel) {
    int iv = __float_as_int(v);
    float a = __int_as_float(__builtin_amdgcn_update_dpp(iv, iv, 0x111, 0xF, 0xF, false)); // row_shr:1
    float b = __int_as_float(__builtin_amdgcn_update_dpp(iv, iv, 0x142, 0xF, 0xF, false)); // row_bcast:15
    return bsel ? b : a;
}

__device__ __forceinline__ void bput(float* p, float v) {
    __hip_atomic_store((unsigned int*)p, __float_as_uint(v),
                       __ATOMIC_RELAXED, __HIP_MEMORY_SCOPE_AGENT);
}
__device__ __forceinline__ unsigned int bgetu(const float* p) {
    return __hip_atomic_load((const unsigned int*)p,
                             __ATOMIC_RELAXED, __HIP_MEMORY_SCOPE_AGENT);
}

// issue SCH relaxed loads into regs; no use -> wait deferred to uvalid
__device__ __forceinline__ void uissue(const float* src, float* dst) {
#pragma unroll
    for (int q = 0; q < SCH; ++q) dst[q] = __uint_as_float(bgetu(src + q));
}
__device__ __forceinline__ bool uvalid(const float* dst) {
    bool ok = true;
#pragma unroll
    for (int q = 0; q < SCH; ++q) ok &= (__float_as_uint(dst[q]) != SENTU);
    return ok;
}
__device__ __forceinline__ void upoll(const float* src, float* dst) {
    for (;;) {
        uissue(src, dst);
        if (uvalid(dst)) return;
        __builtin_amdgcn_s_sleep(1);
    }
}

// p for one chunk: SCH columns from per-lane base (clamped), scalar LDS reads
__device__ __forceinline__ void pload(const float* p_s, int base, float* dst) {
#pragma unroll
    for (int q = 0; q < SCH; ++q) {
        int idx = base + q;
        idx = idx < 0 ? 0 : (idx > NN - 1 ? NN - 1 : idx);
        dst[q] = p_s[idx];
    }
}

template<bool TOP, bool BOT, bool EDGE>
__device__ __forceinline__ void chunk16(
    int cs, int lane, bool l0, bool bsel, float t0, float t1,
    float& v0, float& v1, float& u1, float& u2, float upl,
    float4& acc, const float* upc, const float* pc,
    float* __restrict__ bnd_my, float* __restrict__ outp)
{
#pragma unroll
    for (int u = 0; u < SCH; ++u) {
        const int s = cs + u;
        const int j = s - lane;          // off(l) = l, skew 63
        float a, b;
        if (TOP) {
            a = l0 ? ((s == 0) ? 0.0f : BIGK) : u2;
            b = l0 ? BIGK : u1;
        } else {
            float upj  = upc[u];
            float upjm = (u == 0) ? upl : upc[u - 1];
            a = l0 ? upjm : u2;
            b = l0 ? upj  : u1;
        }
        float pj = pc[u];
        float d0 = t0 - pj;
        float val0 = fmaf(d0, d0, softmin3s(a, b, v0));      // row 2l, col j
        float d1 = t1 - pj;
        float val1 = fmaf(d1, d1, softmin3s(v0, val0, v1));  // row 2l+1, col j
        if (EDGE) {
            bool vj = (unsigned)j < (unsigned)NN;
            val0 = vj ? val0 : BIGK;
            val1 = vj ? val1 : BIGK;
        }
        if (!BOT) {
            // lane63: j = s-63, j%4 == (u+1)%4. collect 4 cols, publish when j%4==3 (u%4==2)
            switch ((u + 1) & 3) {
                case 0: acc.x = val1; break;
                case 1: acc.y = val1; break;
                case 2: acc.z = val1; break;
                case 3: acc.w = val1; break;
            }
            if ((u & 3) == 2) {
                int base = j - 3;
                if (lane == 63 && (!EDGE || (unsigned)base <= (unsigned)(NN - 4))) {
                    bput(bnd_my + base + 0, acc.x);
                    bput(bnd_my + base + 1, acc.y);
                    bput(bnd_my + base + 2, acc.z);
                    bput(bnd_my + base + 3, acc.w);
                }
            }
        } else if (EDGE) {
            if (lane == 63 && s == OUTS) outp[0] = val1 * IK2f;
        }
        v0 = val0; v1 = val1;
        u2 = u1;
        u1 = nbr1(val1, bsel);   // neighbor's v1 @ s, consumed at s+1 (pure VALU)
    }
}

template<bool TOP, bool BOT>
__device__ __forceinline__ void chunk_iter(
    int ci, int lane, bool l0, bool bsel, float t0, float t1,
    float& v0, float& v1, float& u1, float& u2, float& upl,
    float4& acc,
    float* upC, float* upN, float* pcC, float* pcN,
    const float* p_s, const float* __restrict__ bnd_up, float* __restrict__ bnd_my,
    float* __restrict__ outp)
{
    const int cs = SCH * ci;
    if (!TOP && cs < NN) {
        if (!uvalid(upC)) upoll(bnd_up + cs, upC);        // fast path: issued last chunk
        if (cs + SCH < NN) uissue(bnd_up + cs + SCH, upN); // issue for next chunk, no wait
    }
    if (ci + 1 < NCI) pload(p_s, cs + SCH - lane, pcN);

    const bool edge = (ci < 4) || (ci >= 256);
    if (edge) chunk16<TOP, BOT, true >(cs, lane, l0, bsel, t0, t1, v0, v1, u1, u2,
                                       upl, acc, upC, pcC, bnd_my, outp);
    else      chunk16<TOP, BOT, false>(cs, lane, l0, bsel, t0, t1, v0, v1, u1, u2,
                                       upl, acc, upC, pcC, bnd_my, outp);
    if (!TOP) upl = upC[SCH - 1];
}

template<bool TOP, bool BOT>
__device__ void stripe(int b, int lane, const float* __restrict__ target,
                       const float* p_s, float* bnd, float* outp)
{
    const float t0 = target[128 * b + 2 * lane]     * SQK2f;
    const float t1 = target[128 * b + 2 * lane + 1] * SQK2f;
    float* bnd_my = bnd + (size_t)b * NN;
    const float* bnd_up = bnd + (size_t)(b - 1) * NN;
    const bool l0 = (lane == 0);
    const bool bsel = (lane != 0) && ((lane & 15) == 0);   // lanes 16/32/48: row-crossing

    float v0 = BIGK, v1 = BIGK, u1 = BIGK, u2 = BIGK, upl = BIGK;
    float4 acc = {BIGK, BIGK, BIGK, BIGK};
    float upA[SCH], upB[SCH];
    float pcA[SCH], pcB[SCH];

    pload(p_s, -lane, pcA);
    if (!TOP) uissue(bnd_up, upA);   // prologue issue for chunk 0

    for (int cp = 0; cp < NCI / 2; ++cp) {
        chunk_iter<TOP, BOT>(2 * cp,     lane, l0, bsel, t0, t1, v0, v1, u1, u2, upl, acc,
                             upA, upB, pcA, pcB, p_s, bnd_up, bnd_my, outp);
        chunk_iter<TOP, BOT>(2 * cp + 1, lane, l0, bsel, t0, t1, v0, v1, u1, u2, upl, acc,
                             upB, upA, pcB, pcA, p_s, bnd_up, bnd_my, outp);
    }
}

__global__ __launch_bounds__(64, 1) void sdtw_pipe16(const float* __restrict__ pred,
                                                     const float* __restrict__ target,
                                                     float* __restrict__ out,
                                                     float* __restrict__ bnd)
{
    __shared__ float p_s[NN];
    const int lane = threadIdx.x;
    const int bid = blockIdx.x;
    const int b = (bid & 7) * 4 + (bid >> 3);   // group stripe-neighbors per XCD
    for (int i = lane; i < NN; i += 64) p_s[i] = pred[i] * SQK2f;
    __syncthreads();
    if (b == 0)                stripe<true , false>(b, lane, target, p_s, bnd, out);
    else if (b == NBLK - 1)    stripe<false, true >(b, lane, target, p_s, bnd, out);
    else                       stripe<false, false>(b, lane, target, p_s, bnd, out);
}

extern "C" void kernel_launch(void* const* d_in, const int* in_sizes, int n_in,
                              void* d_out, int out_size, void* d_ws, size_t ws_size,
                              hipStream_t stream) {
    const float* pred   = (const float*)d_in[0];
    const float* target = (const float*)d_in[1];
    float* out = (float*)d_out;

    const size_t need = (size_t)NBLK * NN * sizeof(float);
    if (ws_size >= need) {
        float* bnd = (float*)d_ws;
        hipMemsetAsync(d_ws, 0xFF, need, stream);   // NaN-sentinel fill (value-carried readiness)
        sdtw_pipe16<<<dim3(NBLK), dim3(64), 0, stream>>>(pred, target, out, bnd);
    } else {
        dilate_sdtw<<<dim3(1), dim3(1024), 0, stream>>>(pred, target, out);
    }
}